// Round 14
// baseline (937.973 us; speedup 1.0000x reference)
//
#include <hip/hip_runtime.h>
#include <math.h>

// LotkaVolterra neural-SDE rollout. P=4096, H=256, 100 sequential steps.
// R14 = R13 + two micro-cuts:
//  - LDS row stride SH 264 -> 268 elems (S=134 dwords, 6 mod 8): b128 A-read
//    bank-starts spread 8->16 distinct, epilogue write quad-groups 2->4
//    distinct -> roughly halves bank conflicts on the LDS-bound pipe.
//  - prep_cfeat parallelized: grid 99 (block per t), per-block exact fp32
//    tval chain in-register (~400 cyc), ~12us -> ~2us.
// Geometry (R9/R13): 16 waves (NT=1024, 4/SIMD), 1 col-group/wave, 1 block/CU,
// W1/W2 fragments in AGPRs (64) + 64 VGPR work = full register file.

#define PP 4096
#define HH 256
#define LT 100
#define PB 16
#define SH 268          // bf16 LDS row stride: 536 B (134 dwords, 6 mod 8)
#define NT 1024

typedef __attribute__((ext_vector_type(8))) short short8;
typedef __attribute__((ext_vector_type(4))) short short4v;
typedef __attribute__((ext_vector_type(4))) float float4v;

__device__ __forceinline__ float softplus_fast(float x) {
    const float e = __expf(-fabsf(x));
    return fmaxf(x, 0.0f) + __logf(1.0f + e);
}
__device__ __forceinline__ unsigned short f2bf(float f) {   // RNE fp32->bf16
    unsigned int u = __float_as_uint(f);
    u += 0x7fffu + ((u >> 16) & 1u);
    return (unsigned short)(u >> 16);
}
__device__ __forceinline__ float4 ldg4(const float* p) { return *(const float4*)p; }

// ---- parallel prologue: block b handles t = b+1 ----
// cfeat[t][col] = b0[col] + tval(t)*W0[2][col] + tn*W0[3][col]
//                + x1*(W0[4]+W0[6])[col] + x2*(W0[5]+W0[7])[col]
__global__ void prep_cfeat(const float* __restrict__ W0, const float* __restrict__ b0,
                           const float* __restrict__ feature_init,
                           const float* __restrict__ tn_store,
                           const float* __restrict__ x1_store,
                           const float* __restrict__ x2_store,
                           float* __restrict__ cfeat) {
    const int t = blockIdx.x + 1;             // 1..99
    const int col = threadIdx.x;
    // exact sequential fp32 tval chain (matches ref's scan accumulation)
    float tval = feature_init[0];
    for (int i = 0; i < t; ++i) tval += 0.1f;
    const float tn = tn_store[t - 1], x1 = x1_store[t - 1], x2 = x2_store[t - 1];
    const float w2c = W0[2 * 256 + col], w3c = W0[3 * 256 + col];
    const float w46 = W0[4 * 256 + col] + W0[6 * 256 + col];
    const float w57 = W0[5 * 256 + col] + W0[7 * 256 + col];
    cfeat[t * 256 + col] = b0[col] + tval * w2c + tn * w3c + x1 * w46 + x2 * w57;
}

// 256->256 bf16 MFMA layer, 1 col-group/wave, B from regs (b16 epilogue).
__device__ __forceinline__ void mfma256_reg1(const short8 (&wf)[8], float bv,
                                             const unsigned short* __restrict__ hin,
                                             unsigned short* __restrict__ hout,
                                             int wv, int lane) {
    const int quad = lane >> 4, col = lane & 15;
    float4v acc = {bv, bv, bv, bv};
    const unsigned short* arow = hin + col * SH + quad * 8;
#pragma unroll
    for (int ks = 0; ks < 8; ++ks) {
        short8 a = *(const short8*)(arow + ks * 32);
        acc = __builtin_amdgcn_mfma_f32_16x16x32_bf16(a, wf[ks], acc, 0, 0, 0);
    }
    // C/D layout: col = lane&15, row p = quad*4 + reg (m89-verified)
#pragma unroll
    for (int r = 0; r < 4; ++r) {
        hout[(quad * 4 + r) * SH + wv * 16 + col] = f2bf(fmaxf(acc[r], 0.0f));
    }
}

__global__ __launch_bounds__(NT, 1)
void lv_kernel(const float* __restrict__ W0, const float* __restrict__ b0,
               const float* __restrict__ W1, const float* __restrict__ b1,
               const float* __restrict__ W2, const float* __restrict__ b2,
               const float* __restrict__ W3, const float* __restrict__ b3,
               const float* __restrict__ obs_init, const float* __restrict__ feature_init,
               const float* __restrict__ path_seed,
               const float* __restrict__ cfeat,
               float* __restrict__ out) {
    __shared__ unsigned short hA[PB * SH];
    __shared__ unsigned short hB[PB * SH];
    __shared__ unsigned short hC[PB * SH];
    __shared__ __align__(16) unsigned short w3l[4096];   // W3 fragments (zero-padded)
    __shared__ __align__(16) float w0l[512];             // W0 rows 0,1
    __shared__ float sc[16][5];                          // wave-0 o3 scratch
    __shared__ float st[PB][2];                          // path state
    __shared__ __align__(16) float pbuf[PB * 202];
    __shared__ __align__(16) float mbuf[PB * 200];
    __shared__ __align__(16) float sbuf[PB * 400];

    const int tid = threadIdx.x;
    const int lane = tid & 63;
    const int wv = tid >> 6;            // wave 0..15; owns col-group wv
    const int quad = lane >> 4;
    const int col = lane & 15;
    const int pbase = blockIdx.x * PB;

    const float DTf = 0.1f;
    const float SQ = 0.31622776601683794f;  // sqrt(0.1)

    // ---- per-wave W1/W2 B-fragments loaded DIRECTLY from global (one-time) ----
    short8 wf1[8], wf2[8];
    {
        const int colc = wv * 16 + col;
#pragma unroll
        for (int ks = 0; ks < 8; ++ks) {
#pragma unroll
            for (int j = 0; j < 8; ++j) {
                const int k = ks * 32 + quad * 8 + j;
                wf1[ks][j] = (short)f2bf(W1[k * 256 + colc]);
                wf2[ks][j] = (short)f2bf(W2[k * 256 + colc]);
            }
        }
    }
    // ---- stage W3 fragments into LDS (zero-padded to 16 cols) ----
    for (int e = tid; e < 4096; e += NT) {
        const int j = e & 7, ln = (e >> 3) & 63, ks = e >> 9;
        const int k = ks * 32 + (ln >> 4) * 8 + j;
        const int n = ln & 15;
        w3l[e] = (n < 5) ? f2bf(W3[k * 5 + n]) : (unsigned short)0;
    }
    if (tid < 512) w0l[tid] = W0[tid];       // rows 0,1

    // step-invariant hoists
    const float bv1 = b1[wv * 16 + col];
    const float bv2 = b2[wv * 16 + col];
    const float b3c = (col < 5) ? b3[col] : 0.0f;

    if (tid < PB) {
        const int p = tid, gp = pbase + p;
        pbuf[p * 202 + 0] = obs_init[gp * 2 + 0];
        pbuf[p * 202 + 101] = obs_init[gp * 2 + 1];
    }

    // ---- t=0 layer 0: wave wv handles path wv, 4 cols/lane (one-time) ----
    {
        const int gp = pbase + wv;
        float xk[8];
        xk[0] = obs_init[gp * 2 + 0];
        xk[1] = obs_init[gp * 2 + 1];
#pragma unroll
        for (int f = 0; f < 6; ++f) xk[2 + f] = feature_init[gp * 6 + f];
        const int c0 = lane * 4;
        const float4 bv = ldg4(b0 + c0);
        float a0 = bv.x, a1 = bv.y, a2 = bv.z, a3 = bv.w;
#pragma unroll
        for (int k = 0; k < 8; ++k) {
            const float4 w = ldg4(W0 + k * HH + c0);
            a0 = fmaf(xk[k], w.x, a0); a1 = fmaf(xk[k], w.y, a1);
            a2 = fmaf(xk[k], w.z, a2); a3 = fmaf(xk[k], w.w, a3);
        }
        short4v o;
        o[0] = (short)f2bf(fmaxf(a0, 0.0f));
        o[1] = (short)f2bf(fmaxf(a1, 0.0f));
        o[2] = (short)f2bf(fmaxf(a2, 0.0f));
        o[3] = (short)f2bf(fmaxf(a3, 0.0f));
        *(short4v*)&hA[wv * SH + c0] = o;
    }
    // preload cfeat for t=1 (4 cols per lane)
    float4 cf = ldg4(cfeat + 256 + lane * 4);

    for (int t = 0; t < LT; ++t) {
        // seeds for this step: wave 0 lanes<16 only (it does the sampling)
        float e0 = 0.0f, e1 = 0.0f;
        if (tid < PB) {
            const int gp = pbase + tid;
            e0 = path_seed[(size_t)t * PP * 2 + gp * 2 + 0];
            e1 = path_seed[(size_t)t * PP * 2 + gp * 2 + 1];
        }

        // ---- layer 0 (t>=1): wave wv = path wv; st from LDS (broadcast read) ----
        if (t > 0) {
            const float s0 = st[wv][0];
            const float s1 = st[wv][1];
            const int c0 = lane * 4;
            const float4 wa = *(const float4*)&w0l[c0];
            const float4 wb = *(const float4*)&w0l[256 + c0];
            short4v o;
            o[0] = (short)f2bf(fmaxf(fmaf(s0, wa.x, fmaf(s1, wb.x, cf.x)), 0.0f));
            o[1] = (short)f2bf(fmaxf(fmaf(s0, wa.y, fmaf(s1, wb.y, cf.y)), 0.0f));
            o[2] = (short)f2bf(fmaxf(fmaf(s0, wa.z, fmaf(s1, wb.z, cf.z)), 0.0f));
            o[3] = (short)f2bf(fmaxf(fmaf(s0, wa.w, fmaf(s1, wb.w, cf.w)), 0.0f));
            *(short4v*)&hA[wv * SH + c0] = o;
        }
        // prefetch next step's cfeat
        {
            const int ti = (t + 1 < LT) ? (t + 1) : (LT - 1);
            cf = ldg4(cfeat + ti * 256 + lane * 4);
        }
        __syncthreads();                       // B: h0 (hA) ready

        mfma256_reg1(wf1, bv1, hA, hB, wv, lane);   // h1 = relu(h0 @ W1 + b1)
        __syncthreads();                       // C: h1 (hB) ready
        mfma256_reg1(wf2, bv2, hB, hC, wv, lane);   // h2 = relu(h1 @ W2 + b2)
        __syncthreads();                       // D: h2 (hC) ready

        // ---- layer 3 + sampling: WAVE 0 ONLY (W3 B-frags from LDS) ----
        if (wv == 0) {
            float4v accA = {b3c, b3c, b3c, b3c};
            float4v accB = {0.0f, 0.0f, 0.0f, 0.0f};
            const unsigned short* arow = hC + col * SH + quad * 8;
#pragma unroll
            for (int ks = 0; ks < 4; ++ks) {    // two chains of 4 (halve dep latency)
                short8 a0 = *(const short8*)(arow + ks * 32);
                short8 a1 = *(const short8*)(arow + (ks + 4) * 32);
                short8 b0f = *(const short8*)(w3l + (ks * 64 + lane) * 8);
                short8 b1f = *(const short8*)(w3l + ((ks + 4) * 64 + lane) * 8);
                accA = __builtin_amdgcn_mfma_f32_16x16x32_bf16(a0, b0f, accA, 0, 0, 0);
                accB = __builtin_amdgcn_mfma_f32_16x16x32_bf16(a1, b1f, accB, 0, 0, 0);
            }
            if (col < 5) {
#pragma unroll
                for (int r = 0; r < 4; ++r) sc[quad * 4 + r][col] = accA[r] + accB[r];
            }
            // intra-wave lgkmcnt ordering (same wave writes then reads sc)
            if (lane < 16) {
                const int p = lane;
                const float mu0 = sc[p][0];
                const float mu1 = sc[p][1];
                const float s11 = softplus_fast(sc[p][2]);
                const float s21 = sc[p][3];
                const float s22 = softplus_fast(sc[p][4]);
                const float ps0 = (t == 0) ? pbuf[p * 202 + 0] : st[p][0];
                const float ps1 = (t == 0) ? pbuf[p * 202 + 101] : st[p][1];
                const float n0 = softplus_fast(ps0 + DTf * mu0 + SQ * (s11 * e0));
                const float n1 = softplus_fast(ps1 + DTf * mu1 + SQ * (s21 * e0 + s22 * e1));
                st[p][0] = n0;
                st[p][1] = n1;
                pbuf[p * 202 + (t + 1)] = n0;
                pbuf[p * 202 + 101 + (t + 1)] = n1;
                mbuf[p * 200 + t * 2 + 0] = mu0;
                mbuf[p * 200 + t * 2 + 1] = mu1;
                sbuf[p * 400 + t * 4 + 0] = s11;
                sbuf[p * 400 + t * 4 + 1] = 0.0f;
                sbuf[p * 400 + t * 4 + 2] = s21;
                sbuf[p * 400 + t * 4 + 3] = s22;
            }
        }
        __syncthreads();                       // E: st ready for next layer0
    }

    // ---- coalesced output write phase ----
    float* __restrict__ pdst = out + (size_t)pbase * 202;
    float* __restrict__ mdst = out + (size_t)PP * 202 + (size_t)pbase * 200;
    float* __restrict__ sdst = out + (size_t)PP * 202 + (size_t)PP * 200 + (size_t)pbase * 400;
    for (int i = tid; i < PB * 202 / 4; i += NT) ((float4*)pdst)[i] = ((const float4*)pbuf)[i];
    for (int i = tid; i < PB * 200 / 4; i += NT) ((float4*)mdst)[i] = ((const float4*)mbuf)[i];
    for (int i = tid; i < PB * 400 / 4; i += NT) ((float4*)sdst)[i] = ((const float4*)sbuf)[i];
}

extern "C" void kernel_launch(void* const* d_in, const int* in_sizes, int n_in,
                              void* d_out, int out_size, void* d_ws, size_t ws_size,
                              hipStream_t stream) {
    (void)in_sizes; (void)n_in; (void)out_size; (void)ws_size;
    float* cfeat = (float*)d_ws;             // 100*256 fp32 = 100 KB
    prep_cfeat<<<LT - 1, 256, 0, stream>>>(
        (const float*)d_in[0],   // W0
        (const float*)d_in[1],   // b0
        (const float*)d_in[9],   // feature_init (t0)
        (const float*)d_in[10],  // tn_store
        (const float*)d_in[11],  // x1_store
        (const float*)d_in[12],  // x2_store
        cfeat);
    lv_kernel<<<PP / PB, NT, 0, stream>>>(
        (const float*)d_in[0],   // W0
        (const float*)d_in[1],   // b0
        (const float*)d_in[2],   // W1
        (const float*)d_in[3],   // b1
        (const float*)d_in[4],   // W2
        (const float*)d_in[5],   // b2
        (const float*)d_in[6],   // W3
        (const float*)d_in[7],   // b3
        (const float*)d_in[8],   // obs_init
        (const float*)d_in[9],   // feature_init
        (const float*)d_in[13],  // path_seed
        cfeat,
        (float*)d_out);
}

// Round 15
// 322.904 us; speedup vs baseline: 2.9048x; 2.9048x over previous
//
#include <hip/hip_runtime.h>
#include <math.h>

// LotkaVolterra neural-SDE rollout. P=4096, H=256, 100 sequential steps.
// R15 = R13 (proven best kernel: 257us) + R14's parallel prep_cfeat (the only
// good piece of R14; its SH=268 stride broke 16B row alignment -> misaligned
// ds_read_b128 = 3.4x regression. SH must stay a multiple of 8 elements).
// Geometry: 16 waves (NT=1024, 4/SIMD), 1 col-group/wave, 1 block/CU,
// W1/W2 fragments in AGPRs (64) + 64 VGPR work = full register file.
// Step floor: ~5.1k cyc LDS-pipe (16-wave A-broadcast) + serial wave0 tail.

#define PP 4096
#define HH 256
#define LT 100
#define PB 16
#define SH 264          // bf16 LDS row stride: 528 B = 33*16B (MUST stay 16B-multiple)
#define NT 1024

typedef __attribute__((ext_vector_type(8))) short short8;
typedef __attribute__((ext_vector_type(4))) short short4v;
typedef __attribute__((ext_vector_type(4))) float float4v;

__device__ __forceinline__ float softplus_fast(float x) {
    const float e = __expf(-fabsf(x));
    return fmaxf(x, 0.0f) + __logf(1.0f + e);
}
__device__ __forceinline__ unsigned short f2bf(float f) {   // RNE fp32->bf16
    unsigned int u = __float_as_uint(f);
    u += 0x7fffu + ((u >> 16) & 1u);
    return (unsigned short)(u >> 16);
}
__device__ __forceinline__ float4 ldg4(const float* p) { return *(const float4*)p; }

// ---- parallel prologue: block b handles t = b+1 (R14-verified correct) ----
__global__ void prep_cfeat(const float* __restrict__ W0, const float* __restrict__ b0,
                           const float* __restrict__ feature_init,
                           const float* __restrict__ tn_store,
                           const float* __restrict__ x1_store,
                           const float* __restrict__ x2_store,
                           float* __restrict__ cfeat) {
    const int t = blockIdx.x + 1;             // 1..99
    const int col = threadIdx.x;
    // exact sequential fp32 tval chain (matches ref's scan accumulation)
    float tval = feature_init[0];
    for (int i = 0; i < t; ++i) tval += 0.1f;
    const float tn = tn_store[t - 1], x1 = x1_store[t - 1], x2 = x2_store[t - 1];
    const float w2c = W0[2 * 256 + col], w3c = W0[3 * 256 + col];
    const float w46 = W0[4 * 256 + col] + W0[6 * 256 + col];
    const float w57 = W0[5 * 256 + col] + W0[7 * 256 + col];
    cfeat[t * 256 + col] = b0[col] + tval * w2c + tn * w3c + x1 * w46 + x2 * w57;
}

// 256->256 bf16 MFMA layer, 1 col-group/wave, B from regs (b16 epilogue).
__device__ __forceinline__ void mfma256_reg1(const short8 (&wf)[8], float bv,
                                             const unsigned short* __restrict__ hin,
                                             unsigned short* __restrict__ hout,
                                             int wv, int lane) {
    const int quad = lane >> 4, col = lane & 15;
    float4v acc = {bv, bv, bv, bv};
    const unsigned short* arow = hin + col * SH + quad * 8;
#pragma unroll
    for (int ks = 0; ks < 8; ++ks) {
        short8 a = *(const short8*)(arow + ks * 32);
        acc = __builtin_amdgcn_mfma_f32_16x16x32_bf16(a, wf[ks], acc, 0, 0, 0);
    }
    // C/D layout: col = lane&15, row p = quad*4 + reg (m89-verified)
#pragma unroll
    for (int r = 0; r < 4; ++r) {
        hout[(quad * 4 + r) * SH + wv * 16 + col] = f2bf(fmaxf(acc[r], 0.0f));
    }
}

__global__ __launch_bounds__(NT, 1)
void lv_kernel(const float* __restrict__ W0, const float* __restrict__ b0,
               const float* __restrict__ W1, const float* __restrict__ b1,
               const float* __restrict__ W2, const float* __restrict__ b2,
               const float* __restrict__ W3, const float* __restrict__ b3,
               const float* __restrict__ obs_init, const float* __restrict__ feature_init,
               const float* __restrict__ path_seed,
               const float* __restrict__ cfeat,
               float* __restrict__ out) {
    __shared__ unsigned short hA[PB * SH];
    __shared__ unsigned short hB[PB * SH];
    __shared__ unsigned short hC[PB * SH];
    __shared__ __align__(16) unsigned short w3l[4096];   // W3 fragments (zero-padded)
    __shared__ __align__(16) float w0l[512];             // W0 rows 0,1
    __shared__ float sc[16][5];                          // wave-0 o3 scratch
    __shared__ float st[PB][2];                          // path state
    __shared__ __align__(16) float pbuf[PB * 202];
    __shared__ __align__(16) float mbuf[PB * 200];
    __shared__ __align__(16) float sbuf[PB * 400];

    const int tid = threadIdx.x;
    const int lane = tid & 63;
    const int wv = tid >> 6;            // wave 0..15; owns col-group wv
    const int quad = lane >> 4;
    const int col = lane & 15;
    const int pbase = blockIdx.x * PB;

    const float DTf = 0.1f;
    const float SQ = 0.31622776601683794f;  // sqrt(0.1)

    // ---- per-wave W1/W2 B-fragments loaded DIRECTLY from global (one-time) ----
    short8 wf1[8], wf2[8];
    {
        const int colc = wv * 16 + col;
#pragma unroll
        for (int ks = 0; ks < 8; ++ks) {
#pragma unroll
            for (int j = 0; j < 8; ++j) {
                const int k = ks * 32 + quad * 8 + j;
                wf1[ks][j] = (short)f2bf(W1[k * 256 + colc]);
                wf2[ks][j] = (short)f2bf(W2[k * 256 + colc]);
            }
        }
    }
    // ---- stage W3 fragments into LDS (zero-padded to 16 cols) ----
    for (int e = tid; e < 4096; e += NT) {
        const int j = e & 7, ln = (e >> 3) & 63, ks = e >> 9;
        const int k = ks * 32 + (ln >> 4) * 8 + j;
        const int n = ln & 15;
        w3l[e] = (n < 5) ? f2bf(W3[k * 5 + n]) : (unsigned short)0;
    }
    if (tid < 512) w0l[tid] = W0[tid];       // rows 0,1

    // step-invariant hoists
    const float bv1 = b1[wv * 16 + col];
    const float bv2 = b2[wv * 16 + col];
    const float b3c = (col < 5) ? b3[col] : 0.0f;

    if (tid < PB) {
        const int p = tid, gp = pbase + p;
        pbuf[p * 202 + 0] = obs_init[gp * 2 + 0];
        pbuf[p * 202 + 101] = obs_init[gp * 2 + 1];
    }

    // ---- t=0 layer 0: wave wv handles path wv, 4 cols/lane (one-time) ----
    {
        const int gp = pbase + wv;
        float xk[8];
        xk[0] = obs_init[gp * 2 + 0];
        xk[1] = obs_init[gp * 2 + 1];
#pragma unroll
        for (int f = 0; f < 6; ++f) xk[2 + f] = feature_init[gp * 6 + f];
        const int c0 = lane * 4;
        const float4 bv = ldg4(b0 + c0);
        float a0 = bv.x, a1 = bv.y, a2 = bv.z, a3 = bv.w;
#pragma unroll
        for (int k = 0; k < 8; ++k) {
            const float4 w = ldg4(W0 + k * HH + c0);
            a0 = fmaf(xk[k], w.x, a0); a1 = fmaf(xk[k], w.y, a1);
            a2 = fmaf(xk[k], w.z, a2); a3 = fmaf(xk[k], w.w, a3);
        }
        short4v o;
        o[0] = (short)f2bf(fmaxf(a0, 0.0f));
        o[1] = (short)f2bf(fmaxf(a1, 0.0f));
        o[2] = (short)f2bf(fmaxf(a2, 0.0f));
        o[3] = (short)f2bf(fmaxf(a3, 0.0f));
        *(short4v*)&hA[wv * SH + c0] = o;
    }
    // preload cfeat for t=1 (4 cols per lane)
    float4 cf = ldg4(cfeat + 256 + lane * 4);

    for (int t = 0; t < LT; ++t) {
        // seeds for this step: wave 0 lanes<16 only (it does the sampling)
        float e0 = 0.0f, e1 = 0.0f;
        if (tid < PB) {
            const int gp = pbase + tid;
            e0 = path_seed[(size_t)t * PP * 2 + gp * 2 + 0];
            e1 = path_seed[(size_t)t * PP * 2 + gp * 2 + 1];
        }

        // ---- layer 0 (t>=1): wave wv = path wv; st from LDS (broadcast read) ----
        if (t > 0) {
            const float s0 = st[wv][0];
            const float s1 = st[wv][1];
            const int c0 = lane * 4;
            const float4 wa = *(const float4*)&w0l[c0];
            const float4 wb = *(const float4*)&w0l[256 + c0];
            short4v o;
            o[0] = (short)f2bf(fmaxf(fmaf(s0, wa.x, fmaf(s1, wb.x, cf.x)), 0.0f));
            o[1] = (short)f2bf(fmaxf(fmaf(s0, wa.y, fmaf(s1, wb.y, cf.y)), 0.0f));
            o[2] = (short)f2bf(fmaxf(fmaf(s0, wa.z, fmaf(s1, wb.z, cf.z)), 0.0f));
            o[3] = (short)f2bf(fmaxf(fmaf(s0, wa.w, fmaf(s1, wb.w, cf.w)), 0.0f));
            *(short4v*)&hA[wv * SH + c0] = o;
        }
        // prefetch next step's cfeat
        {
            const int ti = (t + 1 < LT) ? (t + 1) : (LT - 1);
            cf = ldg4(cfeat + ti * 256 + lane * 4);
        }
        __syncthreads();                       // B: h0 (hA) ready

        mfma256_reg1(wf1, bv1, hA, hB, wv, lane);   // h1 = relu(h0 @ W1 + b1)
        __syncthreads();                       // C: h1 (hB) ready
        mfma256_reg1(wf2, bv2, hB, hC, wv, lane);   // h2 = relu(h1 @ W2 + b2)
        __syncthreads();                       // D: h2 (hC) ready

        // ---- layer 3 + sampling: WAVE 0 ONLY (W3 B-frags from LDS) ----
        if (wv == 0) {
            float4v accA = {b3c, b3c, b3c, b3c};
            float4v accB = {0.0f, 0.0f, 0.0f, 0.0f};
            const unsigned short* arow = hC + col * SH + quad * 8;
#pragma unroll
            for (int ks = 0; ks < 4; ++ks) {    // two chains of 4 (halve dep latency)
                short8 a0 = *(const short8*)(arow + ks * 32);
                short8 a1 = *(const short8*)(arow + (ks + 4) * 32);
                short8 b0f = *(const short8*)(w3l + (ks * 64 + lane) * 8);
                short8 b1f = *(const short8*)(w3l + ((ks + 4) * 64 + lane) * 8);
                accA = __builtin_amdgcn_mfma_f32_16x16x32_bf16(a0, b0f, accA, 0, 0, 0);
                accB = __builtin_amdgcn_mfma_f32_16x16x32_bf16(a1, b1f, accB, 0, 0, 0);
            }
            if (col < 5) {
#pragma unroll
                for (int r = 0; r < 4; ++r) sc[quad * 4 + r][col] = accA[r] + accB[r];
            }
            // intra-wave lgkmcnt ordering (same wave writes then reads sc)
            if (lane < 16) {
                const int p = lane;
                const float mu0 = sc[p][0];
                const float mu1 = sc[p][1];
                const float s11 = softplus_fast(sc[p][2]);
                const float s21 = sc[p][3];
                const float s22 = softplus_fast(sc[p][4]);
                const float ps0 = (t == 0) ? pbuf[p * 202 + 0] : st[p][0];
                const float ps1 = (t == 0) ? pbuf[p * 202 + 101] : st[p][1];
                const float n0 = softplus_fast(ps0 + DTf * mu0 + SQ * (s11 * e0));
                const float n1 = softplus_fast(ps1 + DTf * mu1 + SQ * (s21 * e0 + s22 * e1));
                st[p][0] = n0;
                st[p][1] = n1;
                pbuf[p * 202 + (t + 1)] = n0;
                pbuf[p * 202 + 101 + (t + 1)] = n1;
                mbuf[p * 200 + t * 2 + 0] = mu0;
                mbuf[p * 200 + t * 2 + 1] = mu1;
                sbuf[p * 400 + t * 4 + 0] = s11;
                sbuf[p * 400 + t * 4 + 1] = 0.0f;
                sbuf[p * 400 + t * 4 + 2] = s21;
                sbuf[p * 400 + t * 4 + 3] = s22;
            }
        }
        __syncthreads();                       // E: st ready for next layer0
    }

    // ---- coalesced output write phase ----
    float* __restrict__ pdst = out + (size_t)pbase * 202;
    float* __restrict__ mdst = out + (size_t)PP * 202 + (size_t)pbase * 200;
    float* __restrict__ sdst = out + (size_t)PP * 202 + (size_t)PP * 200 + (size_t)pbase * 400;
    for (int i = tid; i < PB * 202 / 4; i += NT) ((float4*)pdst)[i] = ((const float4*)pbuf)[i];
    for (int i = tid; i < PB * 200 / 4; i += NT) ((float4*)mdst)[i] = ((const float4*)mbuf)[i];
    for (int i = tid; i < PB * 400 / 4; i += NT) ((float4*)sdst)[i] = ((const float4*)sbuf)[i];
}

extern "C" void kernel_launch(void* const* d_in, const int* in_sizes, int n_in,
                              void* d_out, int out_size, void* d_ws, size_t ws_size,
                              hipStream_t stream) {
    (void)in_sizes; (void)n_in; (void)out_size; (void)ws_size;
    float* cfeat = (float*)d_ws;             // 100*256 fp32 = 100 KB
    prep_cfeat<<<LT - 1, 256, 0, stream>>>(
        (const float*)d_in[0],   // W0
        (const float*)d_in[1],   // b0
        (const float*)d_in[9],   // feature_init (t0)
        (const float*)d_in[10],  // tn_store
        (const float*)d_in[11],  // x1_store
        (const float*)d_in[12],  // x2_store
        cfeat);
    lv_kernel<<<PP / PB, NT, 0, stream>>>(
        (const float*)d_in[0],   // W0
        (const float*)d_in[1],   // b0
        (const float*)d_in[2],   // W1
        (const float*)d_in[3],   // b1
        (const float*)d_in[4],   // W2
        (const float*)d_in[5],   // b2
        (const float*)d_in[6],   // W3
        (const float*)d_in[7],   // b3
        (const float*)d_in[8],   // obs_init
        (const float*)d_in[9],   // feature_init
        (const float*)d_in[13],  // path_seed
        cfeat,
        (float*)d_out);
}